// Round 19
// baseline (407.910 us; speedup 1.0000x reference)
//
#include <hip/hip_runtime.h>
#include <hip/hip_bf16.h>
#include <cstdint>

// DecodingLayer: B=2, S=2048, D=1024, H=16, dh=64, F=1024
// Round-19: fat kernel = attn1 (causal, 1024 blocks) + cross-K/V GEMM
// (512 blocks) in ONE 1536-block dispatch, roles interleaved 2:1 per XCD so
// every CU hosts a mix; GEMM fills attn's idle issue slots (attn: MFMA 11%,
// VALU 50%, residency-insensitive per R12/R13). LDS = 40960B union.
// Buffers: crossK->decB (dead), crossV->vB (dead after self vtrans);
// attn2 reads decB. crossQ = separate 256-block dispatch after LN1.
// All component bodies identical to proven R13/R18 forms.

typedef __attribute__((ext_vector_type(8))) short bf16x8;
typedef __attribute__((ext_vector_type(4))) float f32x4;
typedef unsigned short u16;

#define MFMA16(a, b, c) __builtin_amdgcn_mfma_f32_16x16x32_bf16((a), (b), (c), 0, 0, 0)

__device__ __forceinline__ u16 f2b(float f) {
    __hip_bfloat16 h = __float2bfloat16(f);
    return __builtin_bit_cast(u16, h);
}
__device__ __forceinline__ float b2f(u16 u) {
    return __builtin_bit_cast(float, (uint32_t)u << 16);
}
__device__ __forceinline__ void g2lds16(const u16* g, u16* l) {
    __builtin_amdgcn_global_load_lds((const __attribute__((address_space(1))) void*)g,
                                     (__attribute__((address_space(3))) void*)l, 16, 0, 0);
}

// ---------------- cast f32 -> bf16 ----------------
__global__ __launch_bounds__(256) void cast_bf16_kernel(const float* __restrict__ x,
                                                        u16* __restrict__ y, int n4) {
    int i = blockIdx.x * 256 + threadIdx.x;
    if (i >= n4) return;
    float4 v = reinterpret_cast<const float4*>(x)[i];
    ushort4 o;
    o.x = f2b(v.x); o.y = f2b(v.y); o.z = f2b(v.z); o.w = f2b(v.w);
    reinterpret_cast<ushort4*>(y)[i] = o;
}

// ---------------- transpose+cast all 8 weights: Wt[n][k]=W[k][n] ----------------
__global__ __launch_bounds__(256) void wcast_all_kernel(
    const float* __restrict__ w0, const float* __restrict__ w1,
    const float* __restrict__ w2, const float* __restrict__ w3,
    const float* __restrict__ w4, const float* __restrict__ w5,
    const float* __restrict__ w6, const float* __restrict__ w7,
    u16* __restrict__ wt) {
    __shared__ float t[32][33];
    const float* W;
    switch (blockIdx.z) {
        case 0: W = w0; break; case 1: W = w1; break;
        case 2: W = w2; break; case 3: W = w3; break;
        case 4: W = w4; break; case 5: W = w5; break;
        case 6: W = w6; break; default: W = w7; break;
    }
    u16* Wt = wt + (size_t)blockIdx.z * 1048576;
    int tx = threadIdx.x & 31, ty = threadIdx.x >> 5;
    int bx = blockIdx.x * 32, by = blockIdx.y * 32;
#pragma unroll
    for (int j = 0; j < 4; ++j)
        t[ty + j * 8][tx] = W[(size_t)(by + ty + j * 8) * 1024 + bx + tx];
    __syncthreads();
#pragma unroll
    for (int j = 0; j < 4; ++j)
        Wt[(size_t)(bx + ty + j * 8) * 1024 + by + tx] = f2b(t[tx][ty + j * 8]);
}

// ---------------- per-head V transpose: Vt[b*1024 + dglob][s] = V[b][s][dglob] ----------------
__global__ __launch_bounds__(256) void vtrans_kernel(const u16* __restrict__ V,
                                                     u16* __restrict__ Vt) {
    __shared__ u16 t[32][34];
    const int tx = threadIdx.x & 31, ty = threadIdx.x >> 5;  // ty 0..7
    const int s0 = blockIdx.x * 32, d0 = blockIdx.y * 32, b = blockIdx.z;
    const u16* src = V + (size_t)b * 2048 * 1024;
    u16* dst = Vt + (size_t)b * 1024 * 2048;
#pragma unroll
    for (int j = 0; j < 4; ++j)
        t[ty + j * 8][tx] = src[(size_t)(s0 + ty + j * 8) * 1024 + d0 + tx];
    __syncthreads();
#pragma unroll
    for (int j = 0; j < 4; ++j)
        dst[(size_t)(d0 + ty + j * 8) * 2048 + s0 + tx] = t[tx][ty + j * 8];
}

// ---------------- bf16 GEMM, m97-style + XCD column-chunk remap (128x128) ----------------
__global__ __launch_bounds__(256) void gemm_kernel(
    const u16* __restrict__ A0, const u16* __restrict__ A1,
    const u16* __restrict__ Btb,
    const float* __restrict__ bias0, const float* __restrict__ bias1,
    const float* __restrict__ bias2,
    u16* __restrict__ o0, u16* __restrict__ o1, u16* __restrict__ o2,
    int relu, float oscale0) {
    const int K = 1024;
    __shared__ __align__(16) u16 As[2][128][32];
    __shared__ __align__(16) u16 Bs[2][128][32];
    const int tid = threadIdx.x, lane = tid & 63, w = tid >> 6;
    const int wm = w >> 1, wn = w & 1, l15 = lane & 15, l4 = lane >> 4;
    const int nx = gridDim.x;                    // N tiles (gridDim.y == 32)
    const int fhw = blockIdx.y * nx + blockIdx.x;
    const int cpx = (nx * 32) >> 3;              // blocks per XCD (grid %8==0)
    const int lid = (fhw & 7) * cpx + (fhw >> 3);
    const int bm = (lid & 31) * 128, bn = (lid >> 5) * 128;
    const int which = bn >> 10;
    const u16* A = (which == 0) ? A0 : A1;
    const int srow = lane >> 2, sc = lane & 3;
    const int scs = (sc ^ (srow & 3)) * 8;  // inverse-swizzled source chunk (u16 units)
    const u16* aW = A + (size_t)(bm + w * 16 + srow) * K + scs;
    const u16* bW = Btb + (size_t)(bn + w * 16 + srow) * K + scs;
    f32x4 acc[4][4] = {};

#define GSTAGE(bf, kt)                                                  \
    do {                                                                \
        g2lds16(aW + (kt), &As[bf][w * 16][0]);                         \
        g2lds16(aW + (size_t)64 * K + (kt), &As[bf][64 + w * 16][0]);   \
        g2lds16(bW + (kt), &Bs[bf][w * 16][0]);                         \
        g2lds16(bW + (size_t)64 * K + (kt), &Bs[bf][64 + w * 16][0]);   \
    } while (0)

    const int nt = K / 32;
    GSTAGE(0, 0);
    for (int t = 0; t < nt; ++t) {
        __syncthreads();
        if (t + 1 < nt) GSTAGE((t + 1) & 1, (t + 1) * 32);
        const int bf = t & 1;
        bf16x8 af[4], bfr[4];
#pragma unroll
        for (int m = 0; m < 4; ++m) {
            int row = wm * 64 + m * 16 + l15;
            af[m] = *reinterpret_cast<const bf16x8*>(&As[bf][row][(l4 ^ (l15 & 3)) * 8]);
        }
#pragma unroll
        for (int n = 0; n < 4; ++n) {
            int row = wn * 64 + n * 16 + l15;
            bfr[n] = *reinterpret_cast<const bf16x8*>(&Bs[bf][row][(l4 ^ (l15 & 3)) * 8]);
        }
        __builtin_amdgcn_s_setprio(1);
#pragma unroll
        for (int m = 0; m < 4; ++m)
#pragma unroll
            for (int n = 0; n < 4; ++n)
                acc[m][n] = MFMA16(af[m], bfr[n], acc[m][n]);
        __builtin_amdgcn_s_setprio(0);
    }
#undef GSTAGE
    const float* bias = which == 0 ? bias0 : (which == 1 ? bias1 : bias2);
    u16* outp = which == 0 ? o0 : (which == 1 ? o1 : o2);
    const float osc = which == 0 ? oscale0 : 1.0f;
    const int bnl = bn & 1023;
#pragma unroll
    for (int m = 0; m < 4; ++m) {
#pragma unroll
        for (int n = 0; n < 4; ++n) {
            int col = bnl + wn * 64 + n * 16 + l15;
            float bv = bias[col];
            int row0 = bm + wm * 64 + m * 16 + l4 * 4;
#pragma unroll
            for (int r = 0; r < 4; ++r) {
                float v = (acc[m][n][r] + bv) * osc;
                if (relu) v = fmaxf(v, 0.f);
                outp[(size_t)(row0 + r) * 1024 + col] = f2b(v);
            }
        }
    }
}

// ---------------- 64x128-tile GEMM for N=1024 FFN (2 blocks/CU) ----------------
__global__ __launch_bounds__(256) void gemm64_kernel(
    const u16* __restrict__ A, const u16* __restrict__ Btb,
    const float* __restrict__ bias, u16* __restrict__ outp, int relu) {
    const int K = 1024;
    __shared__ __align__(16) u16 As[2][64][32];
    __shared__ __align__(16) u16 Bs[2][128][32];
    const int tid = threadIdx.x, lane = tid & 63, w = tid >> 6;
    const int wm = w >> 1, wn = w & 1, l15 = lane & 15, l4 = lane >> 4;
    const int fhw = blockIdx.y * 8 + blockIdx.x;   // gridDim = (8, 64)
    const int lid = (fhw & 7) * 64 + (fhw >> 3);
    const int bm = (lid & 63) * 64, bn = (lid >> 6) * 128;
    const int srow = lane >> 2, sc = lane & 3;
    const int scs = (sc ^ (srow & 3)) * 8;
    const u16* aW = A + (size_t)(bm + w * 16 + srow) * K + scs;
    const u16* bW = Btb + (size_t)(bn + w * 16 + srow) * K + scs;
    f32x4 acc[2][4] = {};

#define GSTAGE64(bf, kt)                                                \
    do {                                                                \
        g2lds16(aW + (kt), &As[bf][w * 16][0]);                         \
        g2lds16(bW + (kt), &Bs[bf][w * 16][0]);                         \
        g2lds16(bW + (size_t)64 * K + (kt), &Bs[bf][64 + w * 16][0]);   \
    } while (0)

    const int nt = K / 32;
    GSTAGE64(0, 0);
    for (int t = 0; t < nt; ++t) {
        __syncthreads();
        if (t + 1 < nt) GSTAGE64((t + 1) & 1, (t + 1) * 32);
        const int bf = t & 1;
        bf16x8 af[2], bfr[4];
#pragma unroll
        for (int m = 0; m < 2; ++m) {
            int row = wm * 32 + m * 16 + l15;
            af[m] = *reinterpret_cast<const bf16x8*>(&As[bf][row][(l4 ^ (l15 & 3)) * 8]);
        }
#pragma unroll
        for (int n = 0; n < 4; ++n) {
            int row = wn * 64 + n * 16 + l15;
            bfr[n] = *reinterpret_cast<const bf16x8*>(&Bs[bf][row][(l4 ^ (l15 & 3)) * 8]);
        }
        __builtin_amdgcn_s_setprio(1);
#pragma unroll
        for (int m = 0; m < 2; ++m)
#pragma unroll
            for (int n = 0; n < 4; ++n)
                acc[m][n] = MFMA16(af[m], bfr[n], acc[m][n]);
        __builtin_amdgcn_s_setprio(0);
    }
#undef GSTAGE64
#pragma unroll
    for (int m = 0; m < 2; ++m) {
#pragma unroll
        for (int n = 0; n < 4; ++n) {
            int col = bn + wn * 64 + n * 16 + l15;
            float bv = bias[col];
            int row0 = bm + wm * 32 + m * 16 + l4 * 4;
#pragma unroll
            for (int r = 0; r < 4; ++r) {
                float v = acc[m][n][r] + bv;
                if (relu) v = fmaxf(v, 0.f);
                outp[(size_t)(row0 + r) * 1024 + col] = f2b(v);
            }
        }
    }
}

// ---------------- fused attention (standalone, R13 form) ----------------
template <int CAUSAL>
__global__ __launch_bounds__(256) void attn_kernel(const u16* __restrict__ Qb,
                                                   const u16* __restrict__ Kb,
                                                   const u16* __restrict__ Vt,
                                                   u16* __restrict__ Z) {
    const int S = 2048, D = 1024;
    __shared__ __align__(16) u16 Ks[2][64][64];
    __shared__ __align__(16) u16 Vs[2][64][64];
    __shared__ __align__(16) u16 Ps[4][16][64];
    const int tid = threadIdx.x, lane = tid & 63, w = tid >> 6;
    const int l15 = lane & 15, l4 = lane >> 4;
    const int hwid = blockIdx.x;
    const int wkid = (hwid & 7) * 128 + (hwid >> 3);
    const int qb = wkid & 31, h = (wkid >> 5) & 15, b = wkid >> 9;
    const int q0 = qb * 64 + w * 16;
    const int qg = q0 + l15;
    const size_t baseQ = (size_t)b * S * D + h * 64;
    const size_t baseVt = ((size_t)(b * 16 + h) * 64) * 2048;

    bf16x8 aq0, aq1;
    {
        const u16* qp = Qb + baseQ + (size_t)qg * D + l4 * 8;
        aq0 = *reinterpret_cast<const bf16x8*>(qp);
        aq1 = *reinterpret_cast<const bf16x8*>(qp + 32);
    }
    float lrp0 = 0.f, lrp1 = 0.f, lrp2 = 0.f, lrp3 = 0.f;
    f32x4 Oacc[4] = {};

    const int swzA = (l4 ^ (l15 & 7)) * 8;
    const int swzB = ((l4 + 4) ^ (l15 & 7)) * 8;
    const u16* ksbA = &Ks[0][l15][swzA];
    const u16* ksbB = &Ks[0][l15][swzB];
    const u16* vsbA = &Vs[0][l15][swzA];
    const u16* vsbB = &Vs[0][l15][swzB];
    const int px = l15 & 7;
    u16* pswp[4];
#pragma unroll
    for (int kg = 0; kg < 4; ++kg)
        pswp[kg] = &Ps[w][l15][((2 * kg + (l4 >> 1)) ^ px) * 8 + (l4 & 1) * 4];
    const u16* psrp0 = &Ps[w][l15][((4 * 0 + l4) ^ px) * 8];
    const u16* psrp1 = &Ps[w][l15][((4 * 1 + l4) ^ px) * 8];

    const int srow = lane >> 3, sc8 = lane & 7;
    const int scs = (sc8 ^ srow) * 8;
    const u16* kWn0 = Kb + baseQ + (size_t)(srow + (w * 2 + 0) * 8) * D + scs;
    const u16* kWn1 = Kb + baseQ + (size_t)(srow + (w * 2 + 1) * 8) * D + scs;
    const u16* vWn0 = Vt + baseVt + (size_t)(srow + (w * 2 + 0) * 8) * 2048 + scs;
    const u16* vWn1 = Vt + baseVt + (size_t)(srow + (w * 2 + 1) * 8) * 2048 + scs;

    const int NT = S / 64;
    const int t0pv = CAUSAL ? qb : 0;

    g2lds16(kWn0, &Ks[0][(w * 2 + 0) * 8][0]);
    g2lds16(kWn1, &Ks[0][(w * 2 + 1) * 8][0]);
    kWn0 += 64 * D; kWn1 += 64 * D;
    if (0 >= t0pv) {
        g2lds16(vWn0, &Vs[0][(w * 2 + 0) * 8][0]);
        g2lds16(vWn1, &Vs[0][(w * 2 + 1) * 8][0]);
    }
    vWn0 += 64; vWn1 += 64;

    int tcur = 0;
#define ATILE(B)                                                               \
    do {                                                                       \
        __syncthreads();                                                       \
        if (tcur + 1 < NT) {                                                   \
            g2lds16(kWn0, &Ks[(B) ^ 1][(w * 2 + 0) * 8][0]);                   \
            g2lds16(kWn1, &Ks[(B) ^ 1][(w * 2 + 1) * 8][0]);                   \
            if (tcur + 1 >= t0pv) {                                            \
                g2lds16(vWn0, &Vs[(B) ^ 1][(w * 2 + 0) * 8][0]);               \
                g2lds16(vWn1, &Vs[(B) ^ 1][(w * 2 + 1) * 8][0]);               \
            }                                                                  \
        }                                                                      \
        kWn0 += 64 * D; kWn1 += 64 * D; vWn0 += 64; vWn1 += 64;                \
        const bool dopv = (tcur >= t0pv);                                      \
        const bool maskT = CAUSAL && (tcur == qb);                             \
        bf16x8 vf[2][4];                                                       \
        if (dopv) {                                                            \
            _Pragma("unroll")                                                  \
            for (int n = 0; n < 4; ++n) {                                      \
                vf[0][n] = *reinterpret_cast<const bf16x8*>(                   \
                    vsbA + (B) * 4096 + n * 1024);                             \
                vf[1][n] = *reinterpret_cast<const bf16x8*>(                   \
                    vsbB + (B) * 4096 + n * 1024);                             \
            }                                                                  \
        }                                                                      \
        const f32x4 zero = {0.f, 0.f, 0.f, 0.f};                               \
        _Pragma("unroll")                                                      \
        for (int kg = 0; kg < 4; ++kg) {                                       \
            bf16x8 k0 = *reinterpret_cast<const bf16x8*>(                      \
                ksbA + (B) * 4096 + kg * 1024);                                \
            bf16x8 k1 = *reinterpret_cast<const bf16x8*>(                      \
                ksbB + (B) * 4096 + kg * 1024);                                \
            f32x4 sv = MFMA16(k0, aq0, zero);                                  \
            sv = MFMA16(k1, aq1, sv);                                          \
            float e0 = __builtin_exp2f(sv[0]);                                 \
            float e1 = __builtin_exp2f(sv[1]);                                 \
            float e2 = __builtin_exp2f(sv[2]);                                 \
            float e3 = __builtin_exp2f(sv[3]);                                 \
            lrp0 += e0; lrp1 += e1; lrp2 += e2; lrp3 += e3;                    \
            if (dopv) {                                                        \
                if (maskT) {                                                   \
                    int key = tcur * 64 + kg * 16 + l4 * 4;                    \
                    if (key + 0 < qg) e0 = 0.f;                                \
                    if (key + 1 < qg) e1 = 0.f;                                \
                    if (key + 2 < qg) e2 = 0.f;                                \
                    if (key + 3 < qg) e3 = 0.f;                                \
                }                                                              \
                ushort4 pw;                                                    \
                pw.x = f2b(e0); pw.y = f2b(e1);                                \
                pw.z = f2b(e2); pw.w = f2b(e3);                                \
                *reinterpret_cast<ushort4*>(pswp[kg]) = pw;                    \
            }                                                                  \
        }                                                                      \
        if (dopv) {                                                            \
            asm volatile("s_waitcnt lgkmcnt(0)" ::: "memory");                 \
            __builtin_amdgcn_sched_barrier(0);                                 \
            __builtin_amdgcn_s_setprio(1);                                     \
            bf16x8 pa0 = *reinterpret_cast<const bf16x8*>(psrp0);              \
            bf16x8 pa1 = *reinterpret_cast<const bf16x8*>(psrp1);              \
            _Pragma("unroll")                                                  \
            for (int n = 0; n < 4; ++n)                                        \
                Oacc[n] = MFMA16(vf[0][n], pa0, Oacc[n]);                      \
            _Pragma("unroll")                                                  \
            for (int n = 0; n < 4; ++n)                                        \
                Oacc[n] = MFMA16(vf[1][n], pa1, Oacc[n]);                      \
            __builtin_amdgcn_s_setprio(0);                                     \
        }                                                                      \
        ++tcur;                                                                \
    } while (0)

    for (int i = 0; i < NT / 2; ++i) {
        ATILE(0);
        ATILE(1);
    }
#undef ATILE

    float lr = (lrp0 + lrp1) + (lrp2 + lrp3);
    lr += __shfl_xor(lr, 16);
    lr += __shfl_xor(lr, 32);
    {
        float inv = 1.f / lr;
        int orow = h * 128 + (qg >> 4);
        int oc0 = (qg & 15) * 64;
#pragma unroll
        for (int n = 0; n < 4; ++n) {
            ushort4 o;
            o.x = f2b(Oacc[n][0] * inv); o.y = f2b(Oacc[n][1] * inv);
            o.z = f2b(Oacc[n][2] * inv); o.w = f2b(Oacc[n][3] * inv);
            *reinterpret_cast<ushort4*>(
                &Z[(size_t)b * S * D + (size_t)orow * D + oc0 + n * 16 + l4 * 4]) = o;
        }
    }
}

// ---------------- FAT kernel: attn1 (causal) + cross K/V GEMM, interleaved ----------------
// 1536 blocks; per XCD 192 slots: slot%3<2 -> attn (128/XCD), slot%3==2 -> gemm (64/XCD).
__global__ __launch_bounds__(256) void fat_kernel(
    const u16* __restrict__ Qb, const u16* __restrict__ Kb,
    const u16* __restrict__ Vt, u16* __restrict__ Z,
    const u16* __restrict__ Aenc, const u16* __restrict__ Btb,
    const float* __restrict__ biasK, const float* __restrict__ biasV,
    u16* __restrict__ oK, u16* __restrict__ oV) {
    __shared__ __align__(16) u16 smem[20480];  // 40960B union
    const int tid = threadIdx.x, lane = tid & 63, w = tid >> 6;
    const int bid = blockIdx.x;
    const int xcd = bid & 7, lid2 = bid >> 3;   // lid2 0..191
    const int rrr = lid2 % 3;
    const int l15 = lane & 15, l4 = lane >> 4;

    if (rrr != 2) {
        // ================= attention path (CAUSAL=1) =================
        const int S = 2048, D = 1024;
        u16* KsB = smem;           // [2][64][64]
        u16* VsB = smem + 8192;    // [2][64][64]
        u16* PsB = smem + 16384;   // [4][16][64]
        const int wkid = xcd * 128 + ((lid2 / 3) * 2 + rrr);
        const int qb = wkid & 31, h = (wkid >> 5) & 15, b = wkid >> 9;
        const int q0 = qb * 64 + w * 16;
        const int qg = q0 + l15;
        const size_t baseQ = (size_t)b * S * D + h * 64;
        const size_t baseVt = ((size_t)(b * 16 + h) * 64) * 2048;

        bf16x8 aq0, aq1;
        {
            const u16* qp = Qb + baseQ + (size_t)qg * D + l4 * 8;
            aq0 = *reinterpret_cast<const bf16x8*>(qp);
            aq1 = *reinterpret_cast<const bf16x8*>(qp + 32);
        }
        float lrp0 = 0.f, lrp1 = 0.f, lrp2 = 0.f, lrp3 = 0.f;
        f32x4 Oacc[4] = {};

        const int swzA = (l4 ^ (l15 & 7)) * 8;
        const int swzB = ((l4 + 4) ^ (l15 & 7)) * 8;
        const u16* ksbA = KsB + l15 * 64 + swzA;
        const u16* ksbB = KsB + l15 * 64 + swzB;
        const u16* vsbA = VsB + l15 * 64 + swzA;
        const u16* vsbB = VsB + l15 * 64 + swzB;
        const int px = l15 & 7;
        u16* pswp[4];
#pragma unroll
        for (int kg = 0; kg < 4; ++kg)
            pswp[kg] = PsB + w * 1024 + l15 * 64 +
                       ((2 * kg + (l4 >> 1)) ^ px) * 8 + (l4 & 1) * 4;
        const u16* psrp0 = PsB + w * 1024 + l15 * 64 + ((0 + l4) ^ px) * 8;
        const u16* psrp1 = PsB + w * 1024 + l15 * 64 + ((4 + l4) ^ px) * 8;

        const int srow = lane >> 3, sc8 = lane & 7;
        const int scs = (sc8 ^ srow) * 8;
        const u16* kWn0 = Kb + baseQ + (size_t)(srow + (w * 2 + 0) * 8) * D + scs;
        const u16* kWn1 = Kb + baseQ + (size_t)(srow + (w * 2 + 1) * 8) * D + scs;
        const u16* vWn0 = Vt + baseVt + (size_t)(srow + (w * 2 + 0) * 8) * 2048 + scs;
        const u16* vWn1 = Vt + baseVt + (size_t)(srow + (w * 2 + 1) * 8) * 2048 + scs;

        const int NT = S / 64;
        const int t0pv = qb;

        g2lds16(kWn0, KsB + (w * 2 + 0) * 512);
        g2lds16(kWn1, KsB + (w * 2 + 1) * 512);
        kWn0 += 64 * D; kWn1 += 64 * D;
        if (0 >= t0pv) {
            g2lds16(vWn0, VsB + (w * 2 + 0) * 512);
            g2lds16(vWn1, VsB + (w * 2 + 1) * 512);
        }
        vWn0 += 64; vWn1 += 64;

        int tcur = 0;
#define FTILE(B)                                                               \
    do {                                                                       \
        __syncthreads();                                                       \
        if (tcur + 1 < NT) {                                                   \
            g2lds16(kWn0, KsB + ((B) ^ 1) * 4096 + (w * 2 + 0) * 512);         \
            g2lds16(kWn1, KsB + ((B) ^ 1) * 4096 + (w * 2 + 1) * 512);         \
            if (tcur + 1 >= t0pv) {                                            \
                g2lds16(vWn0, VsB + ((B) ^ 1) * 4096 + (w * 2 + 0) * 512);     \
                g2lds16(vWn1, VsB + ((B) ^ 1) * 4096 + (w * 2 + 1) * 512);     \
            }                                                                  \
        }                                                                      \
        kWn0 += 64 * D; kWn1 += 64 * D; vWn0 += 64; vWn1 += 64;                \
        const bool dopv = (tcur >= t0pv);                                      \
        const bool maskT = (tcur == qb);                                       \
        bf16x8 vf[2][4];                                                       \
        if (dopv) {                                                            \
            _Pragma("unroll")                                                  \
            for (int n = 0; n < 4; ++n) {                                      \
                vf[0][n] = *reinterpret_cast<const bf16x8*>(                   \
                    vsbA + (B) * 4096 + n * 1024);                             \
                vf[1][n] = *reinterpret_cast<const bf16x8*>(                   \
                    vsbB + (B) * 4096 + n * 1024);                             \
            }                                                                  \
        }                                                                      \
        const f32x4 zero = {0.f, 0.f, 0.f, 0.f};                               \
        _Pragma("unroll")                                                      \
        for (int kg = 0; kg < 4; ++kg) {                                       \
            bf16x8 k0 = *reinterpret_cast<const bf16x8*>(                      \
                ksbA + (B) * 4096 + kg * 1024);                                \
            bf16x8 k1 = *reinterpret_cast<const bf16x8*>(                      \
                ksbB + (B) * 4096 + kg * 1024);                                \
            f32x4 sv = MFMA16(k0, aq0, zero);                                  \
            sv = MFMA16(k1, aq1, sv);                                          \
            float e0 = __builtin_exp2f(sv[0]);                                 \
            float e1 = __builtin_exp2f(sv[1]);                                 \
            float e2 = __builtin_exp2f(sv[2]);                                 \
            float e3 = __builtin_exp2f(sv[3]);                                 \
            lrp0 += e0; lrp1 += e1; lrp2 += e2; lrp3 += e3;                    \
            if (dopv) {                                                        \
                if (maskT) {                                                   \
                    int key = tcur * 64 + kg * 16 + l4 * 4;                    \
                    if (key + 0 < qg) e0 = 0.f;                                \
                    if (key + 1 < qg) e1 = 0.f;                                \
                    if (key + 2 < qg) e2 = 0.f;                                \
                    if (key + 3 < qg) e3 = 0.f;                                \
                }                                                              \
                ushort4 pw;                                                    \
                pw.x = f2b(e0); pw.y = f2b(e1);                                \
                pw.z = f2b(e2); pw.w = f2b(e3);                                \
                *reinterpret_cast<ushort4*>(pswp[kg]) = pw;                    \
            }                                                                  \
        }                                                                      \
        if (dopv) {                                                            \
            asm volatile("s_waitcnt lgkmcnt(0)" ::: "memory");                 \
            __builtin_amdgcn_sched_barrier(0);                                 \
            __builtin_amdgcn_s_setprio(1);                                     \
            bf16x8 pa0 = *reinterpret_cast<const bf16x8*>(psrp0);              \
            bf16x8 pa1 = *reinterpret_cast<const bf16x8*>(psrp1);              \
            _Pragma("unroll")                                                  \
            for (int n = 0; n < 4; ++n)                                        \
                Oacc[n] = MFMA16(vf[0][n], pa0, Oacc[n]);                      \
            _Pragma("unroll")                                                  \
            for (int n = 0; n < 4; ++n)                                        \
                Oacc[n] = MFMA16(vf[1][n], pa1, Oacc[n]);                      \
            __builtin_amdgcn_s_setprio(0);                                     \
        }                                                                      \
        ++tcur;                                                                \
    } while (0)

        for (int i = 0; i < NT / 2; ++i) {
            FTILE(0);
            FTILE(1);
        }
#undef FTILE

        float lr = (lrp0 + lrp1) + (lrp2 + lrp3);
        lr += __shfl_xor(lr, 16);
        lr += __shfl_xor(lr, 32);
        float inv = 1.f / lr;
        int orow = h * 128 + (qg >> 4);
        int oc0 = (qg & 15) * 64;
#pragma unroll
        for (int n = 0; n < 4; ++n) {
            ushort4 o;
            o.x = f2b(Oacc[n][0] * inv); o.y = f2b(Oacc[n][1] * inv);
            o.z = f2b(Oacc[n][2] * inv); o.w = f2b(Oacc[n][3] * inv);
            *reinterpret_cast<ushort4*>(
                &Z[(size_t)b * S * D + (size_t)orow * D + oc0 + n * 16 + l4 * 4]) = o;
        }
    } else {
        // ================= cross K/V GEMM path =================
        const int K = 1024;
        u16* AsB = smem;           // [2][128][32]
        u16* BsB = smem + 8192;    // [2][128][32]
        const int wm = w >> 1, wn = w & 1;
        const int lidg = xcd * 64 + lid2 / 3;     // 0..511; XCD-contiguous cols
        const int bm = (lidg & 31) * 128, bn = (lidg >> 5) * 128;
        const int which = bn >> 10;               // 0 -> K, 1 -> V
        const int srow = lane >> 2, sc = lane & 3;
        const int scs = (sc ^ (srow & 3)) * 8;
        const u16* aW = Aenc + (size_t)(bm + w * 16 + srow) * K + scs;
        const u16* bW = Btb + (size_t)(bn + w * 16 + srow) * K + scs;
        f32x4 acc[4][4] = {};

#define FGST(bf, kt)                                                           \
    do {                                                                       \
        g2lds16(aW + (kt), AsB + (bf) * 4096 + w * 512);                       \
        g2lds16(aW + (size_t)64 * K + (kt), AsB + (bf) * 4096 + 2048 + w * 512); \
        g2lds16(bW + (kt), BsB + (bf) * 4096 + w * 512);                       \
        g2lds16(bW + (size_t)64 * K + (kt), BsB + (bf) * 4096 + 2048 + w * 512); \
    } while (0)

        const int nt = K / 32;
        FGST(0, 0);
        for (int t = 0; t < nt; ++t) {
            __syncthreads();
            if (t + 1 < nt) FGST((t + 1) & 1, (t + 1) * 32);
            const int bf = t & 1;
            bf16x8 af[4], bfr[4];
#pragma unroll
            for (int m = 0; m < 4; ++m) {
                int row = wm * 64 + m * 16 + l15;
                af[m] = *reinterpret_cast<const bf16x8*>(
                    AsB + bf * 4096 + row * 32 + (l4 ^ (l15 & 3)) * 8);
            }
#pragma unroll
            for (int n = 0; n < 4; ++n) {
                int row = wn * 64 + n * 16 + l15;
                bfr[n] = *reinterpret_cast<const bf16x8*>(
                    BsB + bf * 4096 + row * 32 + (l4 ^ (l15 & 3)) * 8);
            }
            __builtin_amdgcn_s_setprio(1);
#pragma unroll
            for (int m = 0; m < 4; ++m)
#pragma unroll
                for (int n = 0; n < 4; ++n)
                    acc[m][n] = MFMA16(af[m], bfr[n], acc[m][n]);
            __builtin_amdgcn_s_setprio(0);
        }
#undef FGST
        const float* bias = which == 0 ? biasK : biasV;
        u16* outp = which == 0 ? oK : oV;
        const int bnl = bn & 1023;
#pragma unroll
        for (int m = 0; m < 4; ++m) {
#pragma unroll
            for (int n = 0; n < 4; ++n) {
                int col = bnl + wn * 64 + n * 16 + l15;
                float bv = bias[col];
                int row0 = bm + wm * 64 + m * 16 + l4 * 4;
#pragma unroll
                for (int r = 0; r < 4; ++r) {
                    float v = acc[m][n][r] + bv;
                    outp[(size_t)(row0 + r) * 1024 + col] = f2b(v);
                }
            }
        }
    }
}

// ---------------- fused residual-add + LayerNorm (1 wave per 1024-row) ----------------
__global__ __launch_bounds__(256) void add_ln_kernel(const float* __restrict__ resid,
                                                     const u16* __restrict__ zb,
                                                     const float* __restrict__ g,
                                                     const float* __restrict__ bb,
                                                     float* __restrict__ outF,
                                                     u16* __restrict__ outH) {
    const int row = blockIdx.x * 4 + (threadIdx.x >> 6);
    const int lane = threadIdx.x & 63;
    const float* rp = resid + (size_t)row * 1024;
    const u16* zp = zb + (size_t)row * 1024;
    float v[16];
    float s = 0.f, s2 = 0.f;
#pragma unroll
    for (int k = 0; k < 4; ++k) {
        int col = k * 256 + lane * 4;
        float4 rv = *reinterpret_cast<const float4*>(rp + col);
        ushort4 zv = *reinterpret_cast<const ushort4*>(zp + col);
        float x0 = rv.x + b2f(zv.x);
        float x1 = rv.y + b2f(zv.y);
        float x2 = rv.z + b2f(zv.z);
        float x3 = rv.w + b2f(zv.w);
        v[k * 4 + 0] = x0; v[k * 4 + 1] = x1; v[k * 4 + 2] = x2; v[k * 4 + 3] = x3;
        s += x0 + x1 + x2 + x3;
        s2 += x0 * x0 + x1 * x1 + x2 * x2 + x3 * x3;
    }
#pragma unroll
    for (int o = 32; o >= 1; o >>= 1) {
        s += __shfl_xor(s, o);
        s2 += __shfl_xor(s2, o);
    }
    float mean = s * (1.f / 1024.f);
    float var = s2 * (1.f / 1024.f) - mean * mean;
    float rstd = rsqrtf(var + 1e-5f);
#pragma unroll
    for (int k = 0; k < 4; ++k) {
        int col = k * 256 + lane * 4;
        float4 gv = *reinterpret_cast<const float4*>(g + col);
        float4 bv = *reinterpret_cast<const float4*>(bb + col);
        float o0 = (v[k * 4 + 0] - mean) * rstd * gv.x + bv.x;
        float o1 = (v[k * 4 + 1] - mean) * rstd * gv.y + bv.y;
        float o2 = (v[k * 4 + 2] - mean) * rstd * gv.z + bv.z;
        float o3 = (v[k * 4 + 3] - mean) * rstd * gv.w + bv.w;
        if (outF) {
            float4 o = make_float4(o0, o1, o2, o3);
            *reinterpret_cast<float4*>(outF + (size_t)row * 1024 + col) = o;
        }
        if (outH) {
            ushort4 o;
            o.x = f2b(o0); o.y = f2b(o1); o.z = f2b(o2); o.w = f2b(o3);
            *reinterpret_cast<ushort4*>(outH + (size_t)row * 1024 + col) = o;
        }
    }
}

extern "C" void kernel_launch(void* const* d_in, const int* in_sizes, int n_in,
                              void* d_out, int out_size, void* d_ws, size_t ws_size,
                              hipStream_t stream) {
    const float* enc   = (const float*)d_in[0];
    const float* dec   = (const float*)d_in[1];
    const float* sa_wq = (const float*)d_in[2];  const float* sa_bq = (const float*)d_in[3];
    const float* sa_wk = (const float*)d_in[4];  const float* sa_bk = (const float*)d_in[5];
    const float* sa_wv = (const float*)d_in[6];  const float* sa_bv = (const float*)d_in[7];
    const float* sa_g  = (const float*)d_in[8];  const float* sa_b  = (const float*)d_in[9];
    const float* ca_wq = (const float*)d_in[10]; const float* ca_bq = (const float*)d_in[11];
    const float* ca_wk = (const float*)d_in[12]; const float* ca_bk = (const float*)d_in[13];
    const float* ca_wv = (const float*)d_in[14]; const float* ca_bv = (const float*)d_in[15];
    const float* w1    = (const float*)d_in[18]; const float* b1    = (const float*)d_in[19];
    const float* w2    = (const float*)d_in[20]; const float* b2    = (const float*)d_in[21];
    const float* ca_g  = (const float*)d_in[16]; const float* ca_b  = (const float*)d_in[17];
    const float* fg    = (const float*)d_in[22]; const float* fb    = (const float*)d_in[23];
    float* out = (float*)d_out;

    const size_t WSZ = 1048576;  // 1024*1024
    const size_t ASZ = 4194304;  // 4096*1024

    u16* wt   = (u16*)d_ws;        // 8 transposed bf16 weights (wq,wk,wv,cq,ck,cv,w1,w2)
    u16* decB = wt + 8 * WSZ;      // also reused as cross-K output
    u16* encB = decB + ASZ;
    u16* qB   = encB + ASZ;
    u16* kB   = qB + ASZ;
    u16* vB   = kB + ASZ;          // self V, then cross V (after self vtrans)
    u16* zB   = vB + ASZ;
    float* x1f = (float*)(zB + ASZ);
    u16* xb   = (u16*)(x1f + ASZ); // V^T scratch / LN bf16 output

    // softmax folding: self Q *= (1/sqrt(2048))*log2(e); cross Q *= log2(e)
    const float Q_SCALE_SELF = 0.031879354f;   // 0.022097086912 * 1.4426950409
    const float Q_SCALE_CROSS = 1.4426950408889634f;

    wcast_all_kernel<<<dim3(32, 32, 8), 256, 0, stream>>>(sa_wq, sa_wk, sa_wv, ca_wq,
                                                          ca_wk, ca_wv, w1, w2, wt);
    cast_bf16_kernel<<<4096, 256, 0, stream>>>(dec, decB, (int)(ASZ / 4));
    cast_bf16_kernel<<<4096, 256, 0, stream>>>(enc, encB, (int)(ASZ / 4));

    // ---- self-attention QKV projection (N=3072) ----
    gemm_kernel<<<dim3(24, 32), 256, 0, stream>>>(decB, decB, wt,
                                                  sa_bq, sa_bk, sa_bv, qB, kB, vB,
                                                  0, Q_SCALE_SELF);
    vtrans_kernel<<<dim3(64, 32, 2), 256, 0, stream>>>(vB, xb);  // self V^T

    // ---- FAT: attn1 (causal) + cross K/V GEMM (crossK->decB, crossV->vB) ----
    fat_kernel<<<1536, 256, 0, stream>>>(qB, kB, xb, zB,
                                         encB, wt + 4 * WSZ, ca_bk, ca_bv,
                                         decB, vB);
    add_ln_kernel<<<1024, 256, 0, stream>>>(dec, zB, sa_g, sa_b, x1f, xb);

    // ---- cross-attention: Q projection, then attn2 with crossK (decB) ----
    gemm_kernel<<<dim3(8, 32), 256, 0, stream>>>(xb, xb, wt + 3 * WSZ,
                                                 ca_bq, ca_bq, ca_bq, qB, qB, qB,
                                                 0, Q_SCALE_CROSS);
    vtrans_kernel<<<dim3(64, 32, 2), 256, 0, stream>>>(vB, xb);  // cross V^T
    attn_kernel<0><<<1024, 256, 0, stream>>>(qB, decB, xb, zB);
    add_ln_kernel<<<1024, 256, 0, stream>>>(x1f, zB, ca_g, ca_b, x1f, xb);

    // ---- FFN (64x128 tiles, 512 blocks = 2/CU) ----
    gemm64_kernel<<<dim3(8, 64), 256, 0, stream>>>(xb, wt + 6 * WSZ, b1, qB, 1);
    gemm64_kernel<<<dim3(8, 64), 256, 0, stream>>>(qB, wt + 7 * WSZ, b2, zB, 0);
    add_ln_kernel<<<1024, 256, 0, stream>>>(x1f, zB, fg, fb, out, nullptr);
}

// Round 20
// 329.579 us; speedup vs baseline: 1.2377x; 1.2377x over previous
//
#include <hip/hip_runtime.h>
#include <hip/hip_bf16.h>
#include <cstdint>

// DecodingLayer: B=2, S=2048, D=1024, H=16, dh=64, F=1024
// Round-20: FINAL config = R13/R18 (best measured, 330.5us, reproduced 2x)
// with the two input-cast launches merged into one dispatch.
//  - attn: 4-wave/256-thr, 16 q-rows/wave, KVBLK=64, K+V global_load_lds
//    dbuf, Ps XOR-swizzled, 40960B LDS, causal tile-skip, XCD remap. 87.6us.
//  - GEMM 128x128 + XCD column-chunk remap (L2-resident B panels).
//  - FFN gemm64 (2 blocks/CU); fused residual+LN; single-pass weight
//    transpose-cast.
// Failed avenues (documented): KVBLK=32 pipelines (R14/15), 32-q-rows (R11),
// 8-wave blocks (R17 spill), fat attn+GEMM kernel (R19 VGPR union), phase
// ablation (R16: exp2/P-bounce/PV removal all null -> cadence-bound).

typedef __attribute__((ext_vector_type(8))) short bf16x8;
typedef __attribute__((ext_vector_type(4))) float f32x4;
typedef unsigned short u16;

#define MFMA16(a, b, c) __builtin_amdgcn_mfma_f32_16x16x32_bf16((a), (b), (c), 0, 0, 0)

__device__ __forceinline__ u16 f2b(float f) {
    __hip_bfloat16 h = __float2bfloat16(f);
    return __builtin_bit_cast(u16, h);
}
__device__ __forceinline__ float b2f(u16 u) {
    return __builtin_bit_cast(float, (uint32_t)u << 16);
}
__device__ __forceinline__ void g2lds16(const u16* g, u16* l) {
    __builtin_amdgcn_global_load_lds((const __attribute__((address_space(1))) void*)g,
                                     (__attribute__((address_space(3))) void*)l, 16, 0, 0);
}

// ---------------- cast f32 -> bf16 (dec + enc in one dispatch) ----------------
__global__ __launch_bounds__(256) void cast2_bf16_kernel(const float* __restrict__ x0,
                                                         u16* __restrict__ y0,
                                                         const float* __restrict__ x1,
                                                         u16* __restrict__ y1, int n4) {
    int i = blockIdx.x * 256 + threadIdx.x;
    const float* x = (i < n4) ? x0 : x1;
    u16* y = (i < n4) ? y0 : y1;
    int j = (i < n4) ? i : i - n4;
    float4 v = reinterpret_cast<const float4*>(x)[j];
    ushort4 o;
    o.x = f2b(v.x); o.y = f2b(v.y); o.z = f2b(v.z); o.w = f2b(v.w);
    reinterpret_cast<ushort4*>(y)[j] = o;
}

// ---------------- transpose+cast all 8 weights: Wt[n][k]=W[k][n] ----------------
__global__ __launch_bounds__(256) void wcast_all_kernel(
    const float* __restrict__ w0, const float* __restrict__ w1,
    const float* __restrict__ w2, const float* __restrict__ w3,
    const float* __restrict__ w4, const float* __restrict__ w5,
    const float* __restrict__ w6, const float* __restrict__ w7,
    u16* __restrict__ wt) {
    __shared__ float t[32][33];
    const float* W;
    switch (blockIdx.z) {
        case 0: W = w0; break; case 1: W = w1; break;
        case 2: W = w2; break; case 3: W = w3; break;
        case 4: W = w4; break; case 5: W = w5; break;
        case 6: W = w6; break; default: W = w7; break;
    }
    u16* Wt = wt + (size_t)blockIdx.z * 1048576;
    int tx = threadIdx.x & 31, ty = threadIdx.x >> 5;
    int bx = blockIdx.x * 32, by = blockIdx.y * 32;
#pragma unroll
    for (int j = 0; j < 4; ++j)
        t[ty + j * 8][tx] = W[(size_t)(by + ty + j * 8) * 1024 + bx + tx];
    __syncthreads();
#pragma unroll
    for (int j = 0; j < 4; ++j)
        Wt[(size_t)(bx + ty + j * 8) * 1024 + by + tx] = f2b(t[tx][ty + j * 8]);
}

// ---------------- per-head V transpose: Vt[b*1024 + dglob][s] = V[b][s][dglob] ----------------
__global__ __launch_bounds__(256) void vtrans_kernel(const u16* __restrict__ V,
                                                     u16* __restrict__ Vt) {
    __shared__ u16 t[32][34];
    const int tx = threadIdx.x & 31, ty = threadIdx.x >> 5;  // ty 0..7
    const int s0 = blockIdx.x * 32, d0 = blockIdx.y * 32, b = blockIdx.z;
    const u16* src = V + (size_t)b * 2048 * 1024;
    u16* dst = Vt + (size_t)b * 1024 * 2048;
#pragma unroll
    for (int j = 0; j < 4; ++j)
        t[ty + j * 8][tx] = src[(size_t)(s0 + ty + j * 8) * 1024 + d0 + tx];
    __syncthreads();
#pragma unroll
    for (int j = 0; j < 4; ++j)
        dst[(size_t)(d0 + ty + j * 8) * 2048 + s0 + tx] = t[tx][ty + j * 8];
}

// ---------------- bf16 GEMM, m97-style + XCD column-chunk remap (128x128) ----------------
__global__ __launch_bounds__(256) void gemm_kernel(
    const u16* __restrict__ A0, const u16* __restrict__ A1,
    const u16* __restrict__ Btb,
    const float* __restrict__ bias0, const float* __restrict__ bias1,
    const float* __restrict__ bias2,
    u16* __restrict__ o0, u16* __restrict__ o1, u16* __restrict__ o2,
    int relu, float oscale0) {
    const int K = 1024;
    __shared__ __align__(16) u16 As[2][128][32];
    __shared__ __align__(16) u16 Bs[2][128][32];
    const int tid = threadIdx.x, lane = tid & 63, w = tid >> 6;
    const int wm = w >> 1, wn = w & 1, l15 = lane & 15, l4 = lane >> 4;
    const int nx = gridDim.x;                    // N tiles (gridDim.y == 32)
    const int fhw = blockIdx.y * nx + blockIdx.x;
    const int cpx = (nx * 32) >> 3;              // blocks per XCD (grid %8==0)
    const int lid = (fhw & 7) * cpx + (fhw >> 3);
    const int bm = (lid & 31) * 128, bn = (lid >> 5) * 128;
    const int which = bn >> 10;
    const u16* A = (which == 0) ? A0 : A1;
    const int srow = lane >> 2, sc = lane & 3;
    const int scs = (sc ^ (srow & 3)) * 8;  // inverse-swizzled source chunk (u16 units)
    const u16* aW = A + (size_t)(bm + w * 16 + srow) * K + scs;
    const u16* bW = Btb + (size_t)(bn + w * 16 + srow) * K + scs;
    f32x4 acc[4][4] = {};

#define GSTAGE(bf, kt)                                                  \
    do {                                                                \
        g2lds16(aW + (kt), &As[bf][w * 16][0]);                         \
        g2lds16(aW + (size_t)64 * K + (kt), &As[bf][64 + w * 16][0]);   \
        g2lds16(bW + (kt), &Bs[bf][w * 16][0]);                         \
        g2lds16(bW + (size_t)64 * K + (kt), &Bs[bf][64 + w * 16][0]);   \
    } while (0)

    const int nt = K / 32;
    GSTAGE(0, 0);
    for (int t = 0; t < nt; ++t) {
        __syncthreads();
        if (t + 1 < nt) GSTAGE((t + 1) & 1, (t + 1) * 32);
        const int bf = t & 1;
        bf16x8 af[4], bfr[4];
#pragma unroll
        for (int m = 0; m < 4; ++m) {
            int row = wm * 64 + m * 16 + l15;
            af[m] = *reinterpret_cast<const bf16x8*>(&As[bf][row][(l4 ^ (l15 & 3)) * 8]);
        }
#pragma unroll
        for (int n = 0; n < 4; ++n) {
            int row = wn * 64 + n * 16 + l15;
            bfr[n] = *reinterpret_cast<const bf16x8*>(&Bs[bf][row][(l4 ^ (l15 & 3)) * 8]);
        }
        __builtin_amdgcn_s_setprio(1);
#pragma unroll
        for (int m = 0; m < 4; ++m)
#pragma unroll
            for (int n = 0; n < 4; ++n)
                acc[m][n] = MFMA16(af[m], bfr[n], acc[m][n]);
        __builtin_amdgcn_s_setprio(0);
    }
#undef GSTAGE
    const float* bias = which == 0 ? bias0 : (which == 1 ? bias1 : bias2);
    u16* outp = which == 0 ? o0 : (which == 1 ? o1 : o2);
    const float osc = which == 0 ? oscale0 : 1.0f;
    const int bnl = bn & 1023;
#pragma unroll
    for (int m = 0; m < 4; ++m) {
#pragma unroll
        for (int n = 0; n < 4; ++n) {
            int col = bnl + wn * 64 + n * 16 + l15;
            float bv = bias[col];
            int row0 = bm + wm * 64 + m * 16 + l4 * 4;
#pragma unroll
            for (int r = 0; r < 4; ++r) {
                float v = (acc[m][n][r] + bv) * osc;
                if (relu) v = fmaxf(v, 0.f);
                outp[(size_t)(row0 + r) * 1024 + col] = f2b(v);
            }
        }
    }
}

// ---------------- 64x128-tile GEMM for N=1024 FFN (2 blocks/CU) ----------------
__global__ __launch_bounds__(256) void gemm64_kernel(
    const u16* __restrict__ A, const u16* __restrict__ Btb,
    const float* __restrict__ bias, u16* __restrict__ outp, int relu) {
    const int K = 1024;
    __shared__ __align__(16) u16 As[2][64][32];
    __shared__ __align__(16) u16 Bs[2][128][32];
    const int tid = threadIdx.x, lane = tid & 63, w = tid >> 6;
    const int wm = w >> 1, wn = w & 1, l15 = lane & 15, l4 = lane >> 4;
    const int fhw = blockIdx.y * 8 + blockIdx.x;   // gridDim = (8, 64)
    const int lid = (fhw & 7) * 64 + (fhw >> 3);
    const int bm = (lid & 63) * 64, bn = (lid >> 6) * 128;
    const int srow = lane >> 2, sc = lane & 3;
    const int scs = (sc ^ (srow & 3)) * 8;
    const u16* aW = A + (size_t)(bm + w * 16 + srow) * K + scs;
    const u16* bW = Btb + (size_t)(bn + w * 16 + srow) * K + scs;
    f32x4 acc[2][4] = {};

#define GSTAGE64(bf, kt)                                                \
    do {                                                                \
        g2lds16(aW + (kt), &As[bf][w * 16][0]);                         \
        g2lds16(bW + (kt), &Bs[bf][w * 16][0]);                         \
        g2lds16(bW + (size_t)64 * K + (kt), &Bs[bf][64 + w * 16][0]);   \
    } while (0)

    const int nt = K / 32;
    GSTAGE64(0, 0);
    for (int t = 0; t < nt; ++t) {
        __syncthreads();
        if (t + 1 < nt) GSTAGE64((t + 1) & 1, (t + 1) * 32);
        const int bf = t & 1;
        bf16x8 af[2], bfr[4];
#pragma unroll
        for (int m = 0; m < 2; ++m) {
            int row = wm * 32 + m * 16 + l15;
            af[m] = *reinterpret_cast<const bf16x8*>(&As[bf][row][(l4 ^ (l15 & 3)) * 8]);
        }
#pragma unroll
        for (int n = 0; n < 4; ++n) {
            int row = wn * 64 + n * 16 + l15;
            bfr[n] = *reinterpret_cast<const bf16x8*>(&Bs[bf][row][(l4 ^ (l15 & 3)) * 8]);
        }
        __builtin_amdgcn_s_setprio(1);
#pragma unroll
        for (int m = 0; m < 2; ++m)
#pragma unroll
            for (int n = 0; n < 4; ++n)
                acc[m][n] = MFMA16(af[m], bfr[n], acc[m][n]);
        __builtin_amdgcn_s_setprio(0);
    }
#undef GSTAGE64
#pragma unroll
    for (int m = 0; m < 2; ++m) {
#pragma unroll
        for (int n = 0; n < 4; ++n) {
            int col = bn + wn * 64 + n * 16 + l15;
            float bv = bias[col];
            int row0 = bm + wm * 32 + m * 16 + l4 * 4;
#pragma unroll
            for (int r = 0; r < 4; ++r) {
                float v = acc[m][n][r] + bv;
                if (relu) v = fmaxf(v, 0.f);
                outp[(size_t)(row0 + r) * 1024 + col] = f2b(v);
            }
        }
    }
}

// ---------------- fused attention: R13 form (4-wave, KVBLK=64, Ps swizzled) ----------------
template <int CAUSAL>
__global__ __launch_bounds__(256) void attn_kernel(const u16* __restrict__ Qb,
                                                   const u16* __restrict__ Kb,
                                                   const u16* __restrict__ Vt,
                                                   u16* __restrict__ Z) {
    const int S = 2048, D = 1024;
    __shared__ __align__(16) u16 Ks[2][64][64];
    __shared__ __align__(16) u16 Vs[2][64][64];   // [d][key] per tile
    __shared__ __align__(16) u16 Ps[4][16][64];   // XOR chunk-swizzled, no pad
    const int tid = threadIdx.x, lane = tid & 63, w = tid >> 6;
    const int l15 = lane & 15, l4 = lane >> 4;
    // XCD-aware remap: 1024 = 8*128, bijective
    const int hwid = blockIdx.x;
    const int wkid = (hwid & 7) * 128 + (hwid >> 3);
    const int qb = wkid & 31, h = (wkid >> 5) & 15, b = wkid >> 9;
    const int q0 = qb * 64 + w * 16;
    const int qg = q0 + l15;  // this lane's q-row
    const size_t baseQ = (size_t)b * S * D + h * 64;
    const size_t baseVt = ((size_t)(b * 16 + h) * 64) * 2048;

    bf16x8 aq0, aq1;
    {
        const u16* qp = Qb + baseQ + (size_t)qg * D + l4 * 8;
        aq0 = *reinterpret_cast<const bf16x8*>(qp);
        aq1 = *reinterpret_cast<const bf16x8*>(qp + 32);
    }
    float lrp0 = 0.f, lrp1 = 0.f, lrp2 = 0.f, lrp3 = 0.f;
    f32x4 Oacc[4] = {};

    // hoisted per-lane LDS bases
    const int swzA = (l4 ^ (l15 & 7)) * 8;
    const int swzB = ((l4 + 4) ^ (l15 & 7)) * 8;
    const u16* ksbA = &Ks[0][l15][swzA];
    const u16* ksbB = &Ks[0][l15][swzB];
    const u16* vsbA = &Vs[0][l15][swzA];
    const u16* vsbB = &Vs[0][l15][swzB];
    // Ps XOR-swizzle: logical 16B chunk c at row q stored at chunk c ^ (q&7).
    const int px = l15 & 7;
    u16* pswp[4];
#pragma unroll
    for (int kg = 0; kg < 4; ++kg)
        pswp[kg] = &Ps[w][l15][((2 * kg + (l4 >> 1)) ^ px) * 8 + (l4 & 1) * 4];
    const u16* psrp0 = &Ps[w][l15][((4 * 0 + l4) ^ px) * 8];
    const u16* psrp1 = &Ps[w][l15][((4 * 1 + l4) ^ px) * 8];

    // staging pointers (advance by increment, no per-tile mul)
    const int srow = lane >> 3, sc8 = lane & 7;
    const int scs = (sc8 ^ srow) * 8;
    const u16* kWn0 = Kb + baseQ + (size_t)(srow + (w * 2 + 0) * 8) * D + scs;
    const u16* kWn1 = Kb + baseQ + (size_t)(srow + (w * 2 + 1) * 8) * D + scs;
    const u16* vWn0 = Vt + baseVt + (size_t)(srow + (w * 2 + 0) * 8) * 2048 + scs;
    const u16* vWn1 = Vt + baseVt + (size_t)(srow + (w * 2 + 1) * 8) * 2048 + scs;

    const int NT = S / 64;
    const int t0pv = CAUSAL ? qb : 0;   // first tile carrying PV

    // prologue: stage tile 0 into buf0
    g2lds16(kWn0, &Ks[0][(w * 2 + 0) * 8][0]);
    g2lds16(kWn1, &Ks[0][(w * 2 + 1) * 8][0]);
    kWn0 += 64 * D; kWn1 += 64 * D;
    if (0 >= t0pv) {
        g2lds16(vWn0, &Vs[0][(w * 2 + 0) * 8][0]);
        g2lds16(vWn1, &Vs[0][(w * 2 + 1) * 8][0]);
    }
    vWn0 += 64; vWn1 += 64;

    int tcur = 0;
#define ATILE(B)                                                               \
    do {                                                                       \
        __syncthreads();                                                       \
        if (tcur + 1 < NT) {                                                   \
            g2lds16(kWn0, &Ks[(B) ^ 1][(w * 2 + 0) * 8][0]);                   \
            g2lds16(kWn1, &Ks[(B) ^ 1][(w * 2 + 1) * 8][0]);                   \
            if (tcur + 1 >= t0pv) {                                            \
                g2lds16(vWn0, &Vs[(B) ^ 1][(w * 2 + 0) * 8][0]);               \
                g2lds16(vWn1, &Vs[(B) ^ 1][(w * 2 + 1) * 8][0]);               \
            }                                                                  \
        }                                                                      \
        kWn0 += 64 * D; kWn1 += 64 * D; vWn0 += 64; vWn1 += 64;                \
        const bool dopv = (tcur >= t0pv);                                      \
        const bool maskT = CAUSAL && (tcur == qb);                             \
        bf16x8 vf[2][4];                                                       \
        if (dopv) {                                                            \
            _Pragma("unroll")                                                  \
            for (int n = 0; n < 4; ++n) {                                      \
                vf[0][n] = *reinterpret_cast<const bf16x8*>(                   \
                    vsbA + (B) * 4096 + n * 1024);                             \
                vf[1][n] = *reinterpret_cast<const bf16x8*>(                   \
                    vsbB + (B) * 4096 + n * 1024);                             \
            }                                                                  \
        }                                                                      \
        const f32x4 zero = {0.f, 0.f, 0.f, 0.f};                               \
        _Pragma("unroll")                                                      \
        for (int kg = 0; kg < 4; ++kg) {                                       \
            bf16x8 k0 = *reinterpret_cast<const bf16x8*>(                      \
                ksbA + (B) * 4096 + kg * 1024);                                \
            bf16x8 k1 = *reinterpret_cast<const bf16x8*>(                      \
                ksbB + (B) * 4096 + kg * 1024);                                \
            f32x4 sv = MFMA16(k0, aq0, zero);                                  \
            sv = MFMA16(k1, aq1, sv);                                          \
            float e0 = __builtin_exp2f(sv[0]);                                 \
            float e1 = __builtin_exp2f(sv[1]);                                 \
            float e2 = __builtin_exp2f(sv[2]);                                 \
            float e3 = __builtin_exp2f(sv[3]);                                 \
            lrp0 += e0; lrp1 += e1; lrp2 += e2; lrp3 += e3;                    \
            if (dopv) {                                                        \
                if (maskT) {                                                   \
                    int key = tcur * 64 + kg * 16 + l4 * 4;                    \
                    if (key + 0 < qg) e0 = 0.f;                                \
                    if (key + 1 < qg) e1 = 0.f;                                \
                    if (key + 2 < qg) e2 = 0.f;                                \
                    if (key + 3 < qg) e3 = 0.f;                                \
                }                                                              \
                ushort4 pw;                                                    \
                pw.x = f2b(e0); pw.y = f2b(e1);                                \
                pw.z = f2b(e2); pw.w = f2b(e3);                                \
                *reinterpret_cast<ushort4*>(pswp[kg]) = pw;                    \
            }                                                                  \
        }                                                                      \
        if (dopv) {                                                            \
            asm volatile("s_waitcnt lgkmcnt(0)" ::: "memory");                 \
            __builtin_amdgcn_sched_barrier(0);                                 \
            __builtin_amdgcn_s_setprio(1);                                     \
            bf16x8 pa0 = *reinterpret_cast<const bf16x8*>(psrp0);              \
            bf16x8 pa1 = *reinterpret_cast<const bf16x8*>(psrp1);              \
            _Pragma("unroll")                                                  \
            for (int n = 0; n < 4; ++n)                                        \
                Oacc[n] = MFMA16(vf[0][n], pa0, Oacc[n]);                      \
            _Pragma("unroll")                                                  \
            for (int n = 0; n < 4; ++n)                                        \
                Oacc[n] = MFMA16(vf[1][n], pa1, Oacc[n]);                      \
            __builtin_amdgcn_s_setprio(0);                                     \
        }                                                                      \
        ++tcur;                                                                \
    } while (0)

    for (int i = 0; i < NT / 2; ++i) {
        ATILE(0);
        ATILE(1);
    }
#undef ATILE

    // deferred denominator reduction (once, not per tile)
    float lr = (lrp0 + lrp1) + (lrp2 + lrp3);
    lr += __shfl_xor(lr, 16);
    lr += __shfl_xor(lr, 32);

    // epilogue: lane holds O^T: q = qg (col), d = n*16 + l4*4 + r (row).
    // buggy-merge: z[b,h,q,d] -> Z[b][h*128+(q>>4)][(q&15)*64+d]
    {
        float inv = 1.f / lr;
        int orow = h * 128 + (qg >> 4);
        int oc0 = (qg & 15) * 64;
#pragma unroll
        for (int n = 0; n < 4; ++n) {
            ushort4 o;
            o.x = f2b(Oacc[n][0] * inv); o.y = f2b(Oacc[n][1] * inv);
            o.z = f2b(Oacc[n][2] * inv); o.w = f2b(Oacc[n][3] * inv);
            *reinterpret_cast<ushort4*>(
                &Z[(size_t)b * S * D + (size_t)orow * D + oc0 + n * 16 + l4 * 4]) = o;
        }
    }
}

// ---------------- fused residual-add + LayerNorm (1 wave per 1024-row) ----------------
__global__ __launch_bounds__(256) void add_ln_kernel(const float* __restrict__ resid,
                                                     const u16* __restrict__ zb,
                                                     const float* __restrict__ g,
                                                     const float* __restrict__ bb,
                                                     float* __restrict__ outF,
                                                     u16* __restrict__ outH) {
    const int row = blockIdx.x * 4 + (threadIdx.x >> 6);
    const int lane = threadIdx.x & 63;
    const float* rp = resid + (size_t)row * 1024;
    const u16* zp = zb + (size_t)row * 1024;
    float v[16];
    float s = 0.f, s2 = 0.f;
#pragma unroll
    for (int k = 0; k < 4; ++k) {
        int col = k * 256 + lane * 4;
        float4 rv = *reinterpret_cast<const float4*>(rp + col);
        ushort4 zv = *reinterpret_cast<const ushort4*>(zp + col);
        float x0 = rv.x + b2f(zv.x);
        float x1 = rv.y + b2f(zv.y);
        float x2 = rv.z + b2f(zv.z);
        float x3 = rv.w + b2f(zv.w);
        v[k * 4 + 0] = x0; v[k * 4 + 1] = x1; v[k * 4 + 2] = x2; v[k * 4 + 3] = x3;
        s += x0 + x1 + x2 + x3;
        s2 += x0 * x0 + x1 * x1 + x2 * x2 + x3 * x3;
    }
#pragma unroll
    for (int o = 32; o >= 1; o >>= 1) {
        s += __shfl_xor(s, o);
        s2 += __shfl_xor(s2, o);
    }
    float mean = s * (1.f / 1024.f);
    float var = s2 * (1.f / 1024.f) - mean * mean;
    float rstd = rsqrtf(var + 1e-5f);
#pragma unroll
    for (int k = 0; k < 4; ++k) {
        int col = k * 256 + lane * 4;
        float4 gv = *reinterpret_cast<const float4*>(g + col);
        float4 bv = *reinterpret_cast<const float4*>(bb + col);
        float o0 = (v[k * 4 + 0] - mean) * rstd * gv.x + bv.x;
        float o1 = (v[k * 4 + 1] - mean) * rstd * gv.y + bv.y;
        float o2 = (v[k * 4 + 2] - mean) * rstd * gv.z + bv.z;
        float o3 = (v[k * 4 + 3] - mean) * rstd * gv.w + bv.w;
        if (outF) {
            float4 o = make_float4(o0, o1, o2, o3);
            *reinterpret_cast<float4*>(outF + (size_t)row * 1024 + col) = o;
        }
        if (outH) {
            ushort4 o;
            o.x = f2b(o0); o.y = f2b(o1); o.z = f2b(o2); o.w = f2b(o3);
            *reinterpret_cast<ushort4*>(outH + (size_t)row * 1024 + col) = o;
        }
    }
}

extern "C" void kernel_launch(void* const* d_in, const int* in_sizes, int n_in,
                              void* d_out, int out_size, void* d_ws, size_t ws_size,
                              hipStream_t stream) {
    const float* enc   = (const float*)d_in[0];
    const float* dec   = (const float*)d_in[1];
    const float* sa_wq = (const float*)d_in[2];  const float* sa_bq = (const float*)d_in[3];
    const float* sa_wk = (const float*)d_in[4];  const float* sa_bk = (const float*)d_in[5];
    const float* sa_wv = (const float*)d_in[6];  const float* sa_bv = (const float*)d_in[7];
    const float* sa_g  = (const float*)d_in[8];  const float* sa_b  = (const float*)d_in[9];
    const float* ca_wq = (const float*)d_in[10]; const float* ca_bq = (const float*)d_in[11];
    const float* ca_wk = (const float*)d_in[12]; const float* ca_bk = (const float*)d_in[13];
    const float* ca_wv = (const float*)d_in[14]; const float* ca_bv = (const float*)d_in[15];
    const float* ca_g  = (const float*)d_in[16]; const float* ca_b  = (const float*)d_in[17];
    const float* w1    = (const float*)d_in[18]; const float* b1    = (const float*)d_in[19];
    const float* w2    = (const float*)d_in[20]; const float* b2    = (const float*)d_in[21];
    const float* fg    = (const float*)d_in[22]; const float* fb    = (const float*)d_in[23];
    float* out = (float*)d_out;

    const size_t WSZ = 1048576;  // 1024*1024
    const size_t ASZ = 4194304;  // 4096*1024

    u16* wt   = (u16*)d_ws;        // 8 transposed bf16 weights (wq,wk,wv,cq,ck,cv,w1,w2)
    u16* decB = wt + 8 * WSZ;
    u16* encB = decB + ASZ;
    u16* qB   = encB + ASZ;
    u16* kB   = qB + ASZ;
    u16* vB   = kB + ASZ;
    u16* zB   = vB + ASZ;
    float* x1f = (float*)(zB + ASZ);
    u16* xb   = (u16*)(x1f + ASZ);   // doubles as V^T scratch before each attention

    // softmax folding: self Q *= (1/sqrt(2048))*log2(e); cross Q *= log2(e)
    const float Q_SCALE_SELF = 0.031879354f;   // 0.022097086912 * 1.4426950409
    const float Q_SCALE_CROSS = 1.4426950408889634f;

    wcast_all_kernel<<<dim3(32, 32, 8), 256, 0, stream>>>(sa_wq, sa_wk, sa_wv, ca_wq,
                                                          ca_wk, ca_wv, w1, w2, wt);
    cast2_bf16_kernel<<<8192, 256, 0, stream>>>(dec, decB, enc, encB, (int)(ASZ / 4));

    // ---- self-attention (fused QKV projection, N=3072) ----
    gemm_kernel<<<dim3(24, 32), 256, 0, stream>>>(decB, decB, wt,
                                                  sa_bq, sa_bk, sa_bv, qB, kB, vB,
                                                  0, Q_SCALE_SELF);
    vtrans_kernel<<<dim3(64, 32, 2), 256, 0, stream>>>(vB, xb);
    attn_kernel<1><<<1024, 256, 0, stream>>>(qB, kB, xb, zB);
    add_ln_kernel<<<1024, 256, 0, stream>>>(dec, zB, sa_g, sa_b, x1f, xb);

    // ---- cross-attention (fused Q/K/V: A = xb for Q, encB for K/V) ----
    gemm_kernel<<<dim3(24, 32), 256, 0, stream>>>(xb, encB, wt + 3 * WSZ,
                                                  ca_bq, ca_bk, ca_bv, qB, kB, vB,
                                                  0, Q_SCALE_CROSS);
    vtrans_kernel<<<dim3(64, 32, 2), 256, 0, stream>>>(vB, xb);  // xb dead after cross GEMM
    attn_kernel<0><<<1024, 256, 0, stream>>>(qB, kB, xb, zB);
    add_ln_kernel<<<1024, 256, 0, stream>>>(x1f, zB, ca_g, ca_b, x1f, xb);

    // ---- FFN (64x128 tiles, 512 blocks = 2/CU) ----
    gemm64_kernel<<<dim3(8, 64), 256, 0, stream>>>(xb, wt + 6 * WSZ, b1, qB, 1);
    gemm64_kernel<<<dim3(8, 64), 256, 0, stream>>>(qB, wt + 7 * WSZ, b2, zB, 0);
    add_ln_kernel<<<1024, 256, 0, stream>>>(x1f, zB, fg, fb, out, nullptr);
}